// Round 13
// baseline (23.137 us; speedup 1.0000x reference)
//
#include <hip/hip_runtime.h>
#include <hip/hip_bf16.h>

#define DD 256
#define NROWS 16384
#define TILES 4
#define TROWS 16

typedef float f32x4 __attribute__((ext_vector_type(4)));
typedef __bf16 bf16x4 __attribute__((ext_vector_type(4)));
typedef __bf16 bf16x8 __attribute__((ext_vector_type(8)));

__device__ __forceinline__ bf16x8 cvt8(f32x4 lo, f32x4 hi) {
  bf16x8 v;
#pragma unroll
  for (int j = 0; j < 4; ++j) {
    v[j] = (__bf16)lo[j];
    v[4 + j] = (__bf16)hi[j];
  }
  return v;
}

// ---------------------------------------------------------------------------
// K1: Wc = Wout @ Wv (bf16), bc = bout + Wout @ bv.
// 256 blocks x 1024 threads (16 waves/CU = 4 waves/SIMD -- R11 had 1/SIMD).
// Wave w covers d-slice [16w,+16) with Wout coeffs in regs; lane l owns cols
// 4l..4l+3 (f32x4, 1KB/inst coalesced); 16 independent loads per lane.
// ---------------------------------------------------------------------------
__global__ __launch_bounds__(1024) void wc_bc_kernel(
    const float* __restrict__ Wqkv, const float* __restrict__ bqkv,
    const float* __restrict__ Wout, const float* __restrict__ bout,
    __bf16* __restrict__ Wc, float* __restrict__ bc) {
  __shared__ f32x4 part[16][64];  // 16 KiB
  __shared__ float red[4];
  const int i = blockIdx.x;
  const int t = threadIdx.x;
  const int w = t >> 6, l = t & 63;  // 16 waves
  const float* __restrict__ Wv = Wqkv + 2 * DD * DD;
  const float* __restrict__ bv = bqkv + 2 * DD;
  const float* __restrict__ wrow = Wout + (size_t)i * DD;

  f32x4 wr[4];  // wave's 16 Wout coefficients (uniform broadcast loads)
#pragma unroll
  for (int k = 0; k < 4; ++k) wr[k] = *(const f32x4*)(wrow + w * 16 + k * 4);

  const float* wvp = Wv + (size_t)(w * 16) * DD + l * 4;
  f32x4 a0 = {0.f, 0.f, 0.f, 0.f}, a1 = {0.f, 0.f, 0.f, 0.f};
  f32x4 a2 = {0.f, 0.f, 0.f, 0.f}, a3 = {0.f, 0.f, 0.f, 0.f};
#pragma unroll
  for (int k = 0; k < 4; ++k) {
    a0 += wr[k][0] * *(const f32x4*)(wvp + (size_t)(4 * k + 0) * DD);
    a1 += wr[k][1] * *(const f32x4*)(wvp + (size_t)(4 * k + 1) * DD);
    a2 += wr[k][2] * *(const f32x4*)(wvp + (size_t)(4 * k + 2) * DD);
    a3 += wr[k][3] * *(const f32x4*)(wvp + (size_t)(4 * k + 3) * DD);
  }
  part[w][l] = (a0 + a1) + (a2 + a3);

  if (t < 256) {  // bc partial: waves 0..3
    float p = wrow[t] * bv[t];
#pragma unroll
    for (int off = 32; off > 0; off >>= 1) p += __shfl_down(p, off);
    if (l == 0) red[w] = p;
  }
  __syncthreads();
  if (w == 0) {
    f32x4 s = {0.f, 0.f, 0.f, 0.f};
#pragma unroll
    for (int k = 0; k < 16; ++k) s += part[k][l];
    bf16x4 o;
#pragma unroll
    for (int j = 0; j < 4; ++j) o[j] = (__bf16)s[j];
    *(bf16x4*)(Wc + (size_t)i * DD + l * 4) = o;
    if (l == 0) bc[i] = bout[i] + red[0] + red[1] + red[2] + red[3];
  }
}

// ---------------------------------------------------------------------------
// K2: out = x + x @ Wc^T + bc.
// vs R12: weight fragments hoisted to REGISTERS (fixed per lane across all
// tiles), loaded once directly from global Wc (L2-hot, R5-verified pattern)
// -- no wc_s LDS buffer, no DMA, per-tile LDS reads halved (8 ds_read_b128).
// LDS = 16KB (2 x 8KB bf16 x tiles) -> 4 blocks/CU (launch_bounds(256,4)).
// Grid 1024 = 4 colgroups x 256 rowblocks, TILES=4 (64 rows/block).
// ---------------------------------------------------------------------------
__global__ __launch_bounds__(256, 4) void knn_attn_main(
    const float* __restrict__ x, const __bf16* __restrict__ Wc,
    const float* __restrict__ bc, float* __restrict__ out) {
  __shared__ __bf16 xs[2][TROWS * DD];  // 2 x 8 KiB, swizzled

  const int t = threadIdx.x;
  const int w = t >> 6, l = t & 63;
  const int cg = blockIdx.x >> 8;   // 0..3: col group
  const int rb = blockIdx.x & 255;  // 0..255: row block
  const int C0 = cg * 64;
  const int Rbase = rb * (TILES * TROWS);

  // fragment geometry (R5/R7/R11/R12-verified)
  const int xrow = l & 15, g4 = l >> 4;
  const int rsw = (xrow & 7) << 4;
  const int rA = w * 16 + xrow;  // out-col (local) this lane covers
  const int ocol = C0 + w * 16 + g4 * 4;

  // Weight fragments straight from global Wc, held in regs for all tiles.
  bf16x8 af[8];
  {
    const __bf16* wrp = Wc + (size_t)(C0 + rA) * DD + g4 * 8;
#pragma unroll
    for (int ks = 0; ks < 8; ++ks) af[ks] = *(const bf16x8*)(wrp + ks * 32);
  }
  const f32x4 bias = *(const f32x4*)(bc + ocol);  // bc includes bout

  // staging geometry: thread -> (row sr, 16-float segment sc)
  const int sr = t >> 4, sc = t & 15;
  const int ssw = (sr & 7) << 4;
  const int sbase = sr * 512 + sc * 32;  // bf16 row = 512 B

  {  // prologue: tile 0
    const float* s0 = x + (size_t)(Rbase + sr) * DD + sc * 16;
    f32x4 a = *(const f32x4*)(s0 + 0);
    f32x4 b = *(const f32x4*)(s0 + 4);
    f32x4 c = *(const f32x4*)(s0 + 8);
    f32x4 d = *(const f32x4*)(s0 + 12);
    char* xb = (char*)&xs[0][0];
    *(bf16x8*)(xb + ((sbase + 0) ^ ssw)) = cvt8(a, b);
    *(bf16x8*)(xb + ((sbase + 16) ^ ssw)) = cvt8(c, d);
  }
  __syncthreads();

  for (int i = 0; i < TILES; ++i) {
    f32x4 a, b, c, d;
    if (i + 1 < TILES) {  // issue next tile's loads under compute
      const float* sn =
          x + (size_t)(Rbase + (i + 1) * TROWS + sr) * DD + sc * 16;
      a = *(const f32x4*)(sn + 0);
      b = *(const f32x4*)(sn + 4);
      c = *(const f32x4*)(sn + 8);
      d = *(const f32x4*)(sn + 12);
    }

    // compute tile i: 8 ds_read_b128 + 8 MFMA (weights in regs)
    const char* xb = (const char*)&xs[i & 1][0];
    f32x4 acc = {0.f, 0.f, 0.f, 0.f};
#pragma unroll
    for (int ks = 0; ks < 8; ++ks) {
      const int kb = ks * 64 + g4 * 16;
      bf16x8 bfr = *(const bf16x8*)(xb + ((xrow * 512 + kb) ^ rsw));
      acc = __builtin_amdgcn_mfma_f32_16x16x32_bf16(af[ks], bfr, acc, 0, 0, 0);
    }
    {  // epilogue: D col(l&15)=x-row, rowquad g4*4+reg = out-col (verified)
      const size_t idx = (size_t)(Rbase + i * TROWS + xrow) * DD + ocol;
      f32x4 xres = *(const f32x4*)(x + idx);  // exact fp32, L2-hot
      *(f32x4*)(out + idx) = acc + xres + bias;
    }

    if (i + 1 < TILES) {  // write next tile into the other buffer
      char* xbn = (char*)&xs[(i + 1) & 1][0];
      *(bf16x8*)(xbn + ((sbase + 0) ^ ssw)) = cvt8(a, b);
      *(bf16x8*)(xbn + ((sbase + 16) ^ ssw)) = cvt8(c, d);
    }
    __syncthreads();
  }
}

extern "C" void kernel_launch(void* const* d_in, const int* in_sizes, int n_in,
                              void* d_out, int out_size, void* d_ws, size_t ws_size,
                              hipStream_t stream) {
  const float* x = (const float*)d_in[0];
  const float* Wqkv = (const float*)d_in[1];
  const float* bqkv = (const float*)d_in[2];
  const float* Wout = (const float*)d_in[3];
  const float* bout = (const float*)d_in[4];
  float* out = (float*)d_out;

  __bf16* Wc = (__bf16*)d_ws;                                   // 128 KiB
  float* bc = (float*)((char*)d_ws + DD * DD * sizeof(__bf16)); // +1 KiB

  wc_bc_kernel<<<DD, 1024, 0, stream>>>(Wqkv, bqkv, Wout, bout, Wc, bc);
  knn_attn_main<<<1024, 256, 0, stream>>>(x, Wc, bc, out);
}